// Round 8
// baseline (233.314 us; speedup 1.0000x reference)
//
#include <hip/hip_runtime.h>
#include <hip/hip_bf16.h>
#include <hip/hip_fp8.h>

typedef unsigned char u8;
typedef unsigned short u16;
typedef unsigned int u32;
typedef __attribute__((ext_vector_type(4))) int i32x4;
typedef __attribute__((ext_vector_type(8))) int i32x8;
typedef __attribute__((ext_vector_type(16))) float f32x16;

#define NB 4096
#define ND 512
#define NREPS (3*NB)
#define BM 128
#define BN 256
#define BK 128
#define NKT (ND/BK)      // 4 K-tiles
#define ASZ (BM*BK)      // 16 KiB
#define BSZ (BN*BK)      // 32 KiB
#define SCL 0x7F7F7F7F   // e8m0 scale bytes = 127 -> 1.0

// global -> LDS direct DMA, 16B/lane; LDS dest wave-uniform base + lane*16.
#define GLD16(gp, lp)                                                         \
  __builtin_amdgcn_global_load_lds(                                           \
      (const __attribute__((address_space(1))) void*)(gp),                    \
      (__attribute__((address_space(3))) void*)(lp), 16, 0, 0)

__device__ __forceinline__ u32 pk4(float a, float b, float c, float d) {
  __hip_fp8_e4m3 qa(a), qb(b), qc(c), qd(d);
  return (u32)qa.__x | ((u32)qb.__x << 8) | ((u32)qc.__x << 16) | ((u32)qd.__x << 24);
}

// Fused prep: waves 0..2 convert ts/i1/i2 row r -> fp8 reps + fp32 norms
// (norms from ORIGINAL fp32 -> quantization error only in the cross-dot);
// i1/i2 rows pass through LDS to wave 3 (dist12 + minsq init).
__global__ __launch_bounds__(256) void prep_all(
    const float* __restrict__ ts, const float* __restrict__ i1,
    const float* __restrict__ i2, u8* __restrict__ reps,
    float* __restrict__ norms, float* __restrict__ dist12,
    u32* __restrict__ minsq)
{
  __shared__ float s1[ND], s2[ND];
  const int r = blockIdx.x;
  const int tid = threadIdx.x;
  const int wave = tid >> 6, lane = tid & 63;

  if (wave < 3) {
    const float* src = (wave == 0) ? ts + (size_t)r * ND
                     : (wave == 1) ? i1 + (size_t)r * ND
                     :               i2 + (size_t)r * ND;
    const float4* s4 = (const float4*)src;
    float4 a = s4[lane*2+0];
    float4 b = s4[lane*2+1];
    if (wave == 1) { ((float4*)s1)[lane*2+0] = a; ((float4*)s1)[lane*2+1] = b; }
    if (wave == 2) { ((float4*)s2)[lane*2+0] = a; ((float4*)s2)[lane*2+1] = b; }
    float ss = a.x*a.x + a.y*a.y + a.z*a.z + a.w*a.w
             + b.x*b.x + b.y*b.y + b.z*b.z + b.w*b.w;
    uint2 pk;
    pk.x = pk4(a.x, a.y, a.z, a.w);
    pk.y = pk4(b.x, b.y, b.z, b.w);
    *(uint2*)(reps + (size_t)(wave*NB + r) * ND + lane*8) = pk;
    #pragma unroll
    for (int off = 32; off; off >>= 1) ss += __shfl_down(ss, off);
    if (lane == 0) norms[wave*NB + r] = ss;
  }
  __syncthreads();
  if (wave == 3) {
    float ss = 0.f;
    #pragma unroll
    for (int i = 0; i < 2; ++i) {
      float4 a = ((float4*)s1)[lane*2+i];
      float4 b = ((float4*)s2)[lane*2+i];
      float d0 = a.x - b.x + 1e-6f, d1 = a.y - b.y + 1e-6f;
      float d2 = a.z - b.z + 1e-6f, d3 = a.w - b.w + 1e-6f;
      ss += d0*d0 + d1*d1 + d2*d2 + d3*d3;
    }
    #pragma unroll
    for (int off = 32; off; off >>= 1) ss += __shfl_down(ss, off);
    if (lane == 0) { dist12[r] = sqrtf(ss); minsq[r] = 0x7F800000u; }
  }
}

// Read one 32-byte f8f6f4 operand fragment (8 dwords) from a 128B-row LDS
// tile: lane holds row [row], k-bytes [ks*64 + hi*32 .. +31]; granules are
// XOR-swizzled (slot ^ (row&7)) matching the staging-side source swizzle.
__device__ __forceinline__ i32x8 rd_op(const u8* __restrict__ S, int row,
                                       int ks, int hi) {
  const int sw = row & 7;
  const int s0 = ks*4 + hi*2;
  const i32x4 lo = *(const i32x4*)&S[row*BK + ((s0 ^ sw) << 4)];
  const i32x4 h  = *(const i32x4*)&S[row*BK + (((s0+1) ^ sw) << 4)];
  i32x8 r;
  r[0]=lo[0]; r[1]=lo[1]; r[2]=lo[2]; r[3]=lo[3];
  r[4]=h[0];  r[5]=h[1];  r[6]=h[2];  r[7]=h[3];
  return r;
}

#define MFMA8(a,b,c) __builtin_amdgcn_mfma_scale_f32_32x32x64_f8f6f4(          \
    (a), (b), (c), 0, 0, 0, SCL, 0, SCL)

// Fused distance-GEMM (MX-fp8, scale=1.0) + per-row min + diagonal picks.
// 128x256 tile, BK=128 (fp8 -> same 48 KiB LDS, NKT=4: HALF the per-step
// vmcnt(0) drains that R2..R7 showed to be the bottleneck). 8 waves (2Mx4N),
// wave-tile 64x64 = 2x2 frags of 32x32, mfma_scale_f32_32x32x64_f8f6f4.
// Grid dim3(32,48) M-fastest (R5 lesson: XCD swizzle quadrupled FETCH).
// LDS linear; XOR swizzle on per-lane GLOBAL source granule (m173 pattern).
__global__ __launch_bounds__(512, 4) void gemm_min(
    const u8* __restrict__ reps, const float* __restrict__ norms,
    u32* __restrict__ minsq, float* __restrict__ lpos1,
    float* __restrict__ lpos2)
{
  __shared__ u8 As[ASZ];
  __shared__ u8 Bs[BSZ];
  const int tid  = threadIdx.x;
  const int lane = tid & 63;
  const int wave = tid >> 6;          // 0..7
  const int wr = wave >> 2;           // 0..1 (M half)
  const int wc = wave & 3;            // 0..3 (N quarter)
  const int lc = lane & 31;           // col within 32x32 frag
  const int hi = lane >> 5;           // k-half / row-offset selector

  const int rowBase = blockIdx.x * BM;   // ts rows
  const int colBase = blockIdx.y * BN;   // reps rows

  // Staging: rows are 128 B (8 granules); one GLD16 covers 8 rows.
  // A = 16 chunks (2/wave), B = 32 chunks (4/wave).
  const int rloc = lane >> 3;          // row within 8-row chunk (== r&7)
  const int sp   = lane & 7;           // physical granule slot
  const int g    = sp ^ rloc;          // swizzled source granule
  const u8* srcA[2]; u8* dstA[2];
  const u8* srcB[4]; u8* dstB[4];
  #pragma unroll
  for (int i = 0; i < 2; ++i) {
    const int r = wave*16 + i*8 + rloc;           // tile-local A row
    srcA[i] = reps + (size_t)(rowBase + r) * ND + g*16;
    dstA[i] = &As[(wave*16 + i*8) * BK];
  }
  #pragma unroll
  for (int i = 0; i < 4; ++i) {
    const int r = wave*32 + i*8 + rloc;           // tile-local B row
    srcB[i] = reps + (size_t)(colBase + r) * ND + g*16;
    dstB[i] = &Bs[(wave*32 + i*8) * BK];
  }

  f32x16 acc00 = {}, acc01 = {}, acc10 = {}, acc11 = {};

  for (int kt = 0; kt < NKT; ++kt) {
    const int koff = kt * BK;
    #pragma unroll
    for (int i = 0; i < 2; ++i) GLD16(srcA[i] + koff, dstA[i]);
    #pragma unroll
    for (int i = 0; i < 4; ++i) GLD16(srcB[i] + koff, dstB[i]);
    __syncthreads();   // vmcnt(0) drain + barrier (4x per block, was 8x)

    #pragma unroll
    for (int ks = 0; ks < 2; ++ks) {
      const i32x8 a0 = rd_op(As, wr*64      + lc, ks, hi);
      const i32x8 a1 = rd_op(As, wr*64 + 32 + lc, ks, hi);
      const i32x8 b0 = rd_op(Bs, wc*64      + lc, ks, hi);
      const i32x8 b1 = rd_op(Bs, wc*64 + 32 + lc, ks, hi);
      acc00 = MFMA8(a0, b0, acc00);
      acc01 = MFMA8(a0, b1, acc01);
      acc10 = MFMA8(a1, b0, acc10);
      acc11 = MFMA8(a1, b1, acc11);
    }
    __syncthreads();
  }

  // Epilogue. 32x32 C layout: col = lane&31, row = (reg&3)+8*(reg>>2)+4*hi.
  // A given row's 32 cols (per ni) live in ONE 32-lane half -> 5-step
  // shuffle-xor reduce within the half; both halves reduce their own rows.
  const float nc0 = norms[colBase + wc*64      + lc];
  const float nc1 = norms[colBase + wc*64 + 32 + lc];
  const int   c0g = colBase + wc*64      + lc;
  const int   c1g = colBase + wc*64 + 32 + lc;
  const float INF = __builtin_inff();

#define EPI(MI, ACCA, ACCB)                                                   \
  { _Pragma("unroll")                                                         \
    for (int reg = 0; reg < 16; ++reg) {                                      \
      const int r_g = rowBase + wr*64 + (MI)*32 + (reg&3) + 8*(reg>>2) + 4*hi;\
      const float ntr = norms[r_g];                                           \
      const float sq0 = ntr + nc0 - 2.0f * (ACCA)[reg];                       \
      const float sq1 = ntr + nc1 - 2.0f * (ACCB)[reg];                       \
      if (c0g == r_g + NB)   lpos1[r_g] = sq0;                                \
      if (c0g == r_g + 2*NB) lpos2[r_g] = sq0;                                \
      if (c1g == r_g + NB)   lpos1[r_g] = sq1;                                \
      if (c1g == r_g + 2*NB) lpos2[r_g] = sq1;                                \
      const bool e0 = (c0g == r_g) || (c0g == r_g+NB) || (c0g == r_g+2*NB);   \
      const bool e1 = (c1g == r_g) || (c1g == r_g+NB) || (c1g == r_g+2*NB);   \
      float vm = fminf(e0 ? INF : fmaxf(sq0, 0.0f),                           \
                       e1 ? INF : fmaxf(sq1, 0.0f));                          \
      _Pragma("unroll")                                                       \
      for (int off = 1; off < 32; off <<= 1)                                  \
        vm = fminf(vm, __shfl_xor(vm, off));                                  \
      if (lc == 0)                                                            \
        atomicMin(minsq + r_g, __float_as_uint(vm));                          \
    } }

  EPI(0, acc00, acc01);
  EPI(1, acc10, acc11);
}

__global__ __launch_bounds__(1024) void finalize(
    const float* __restrict__ lpos1, const float* __restrict__ lpos2,
    const float* __restrict__ dist12, const u32* __restrict__ minsq,
    float* __restrict__ out)
{
  __shared__ float red[16];
  const int tid = threadIdx.x;
  float s = 0.f;
  for (int r = tid; r < NB; r += 1024) {
    float l1 = sqrtf(fmaxf(lpos1[r], 0.f));
    float l2 = sqrtf(fmaxf(lpos2[r], 0.f));
    float neg = sqrtf(__uint_as_float(minsq[r]));   // already clamped >= 0
    float pos = l1 + l2 + dist12[r];
    s += fmaxf(pos - neg + 0.1f, 0.f) + fmaxf(l1, l2);
  }
  #pragma unroll
  for (int off = 32; off; off >>= 1) s += __shfl_down(s, off);
  if ((tid & 63) == 0) red[tid >> 6] = s;
  __syncthreads();
  if (tid == 0) {
    float t = 0.f;
    #pragma unroll
    for (int i = 0; i < 16; ++i) t += red[i];
    out[0] = t * (1.0f / NB);
  }
}

extern "C" void kernel_launch(void* const* d_in, const int* in_sizes, int n_in,
                              void* d_out, int out_size, void* d_ws, size_t ws_size,
                              hipStream_t stream) {
  const float* ts = (const float*)d_in[0];
  const float* i1 = (const float*)d_in[1];
  const float* i2 = (const float*)d_in[2];
  float* out = (float*)d_out;

  char* p = (char*)d_ws;
  u8* reps     = (u8*)p;             p += (size_t)NREPS * ND * sizeof(u8);   // 6.3 MB
  float* norms = (float*)p;          p += (size_t)NREPS * sizeof(float);
  float* dist12 = (float*)p;         p += (size_t)NB * sizeof(float);
  u32* minsq   = (u32*)p;            p += (size_t)NB * sizeof(u32);
  float* lpos1 = (float*)p;          p += (size_t)NB * sizeof(float);
  float* lpos2 = (float*)p;          p += (size_t)NB * sizeof(float);

  prep_all<<<NB, 256, 0, stream>>>(ts, i1, i2, reps, norms, dist12, minsq);
  dim3 grid(NB / BM, NREPS / BN);   // 32 x 48, M-fastest (L2 locality)
  gemm_min<<<grid, 512, 0, stream>>>(reps, norms, minsq, lpos1, lpos2);
  finalize<<<1, 1024, 0, stream>>>(lpos1, lpos2, dist12, minsq, out);
}

// Round 9
// 168.086 us; speedup vs baseline: 1.3881x; 1.3881x over previous
//
#include <hip/hip_runtime.h>
#include <hip/hip_bf16.h>
#include <hip/hip_fp8.h>

typedef unsigned char u8;
typedef unsigned short u16;
typedef unsigned int u32;
typedef __attribute__((ext_vector_type(4))) int i32x4;
typedef __attribute__((ext_vector_type(8))) int i32x8;
typedef __attribute__((ext_vector_type(16))) float f32x16;

#define NB 4096
#define ND 512
#define NREPS (3*NB)
#define BM 128
#define BN 128
#define BK 128
#define NKT (ND/BK)      // 4 K-tiles
#define ASZ (BM*BK)      // 16 KiB
#define BSZ (BN*BK)      // 16 KiB
#define SCL 0x7F7F7F7F   // e8m0 scale bytes = 127 -> 1.0

// global -> LDS direct DMA, 16B/lane; LDS dest wave-uniform base + lane*16.
#define GLD16(gp, lp)                                                         \
  __builtin_amdgcn_global_load_lds(                                           \
      (const __attribute__((address_space(1))) void*)(gp),                    \
      (__attribute__((address_space(3))) void*)(lp), 16, 0, 0)

__device__ __forceinline__ u32 pk4(float a, float b, float c, float d) {
  __hip_fp8_e4m3 qa(a), qb(b), qc(c), qd(d);
  return (u32)qa.__x | ((u32)qb.__x << 8) | ((u32)qc.__x << 16) | ((u32)qd.__x << 24);
}

// Fused prep: waves 0..2 convert ts/i1/i2 row r -> fp8 reps + fp32 norms
// (norms from ORIGINAL fp32 -> quantization error only in the cross-dot);
// i1/i2 rows pass through LDS to wave 3 (dist12 + minsq init).
__global__ __launch_bounds__(256) void prep_all(
    const float* __restrict__ ts, const float* __restrict__ i1,
    const float* __restrict__ i2, u8* __restrict__ reps,
    float* __restrict__ norms, float* __restrict__ dist12,
    u32* __restrict__ minsq)
{
  __shared__ float s1[ND], s2[ND];
  const int r = blockIdx.x;
  const int tid = threadIdx.x;
  const int wave = tid >> 6, lane = tid & 63;

  if (wave < 3) {
    const float* src = (wave == 0) ? ts + (size_t)r * ND
                     : (wave == 1) ? i1 + (size_t)r * ND
                     :               i2 + (size_t)r * ND;
    const float4* s4 = (const float4*)src;
    float4 a = s4[lane*2+0];
    float4 b = s4[lane*2+1];
    if (wave == 1) { ((float4*)s1)[lane*2+0] = a; ((float4*)s1)[lane*2+1] = b; }
    if (wave == 2) { ((float4*)s2)[lane*2+0] = a; ((float4*)s2)[lane*2+1] = b; }
    float ss = a.x*a.x + a.y*a.y + a.z*a.z + a.w*a.w
             + b.x*b.x + b.y*b.y + b.z*b.z + b.w*b.w;
    uint2 pk;
    pk.x = pk4(a.x, a.y, a.z, a.w);
    pk.y = pk4(b.x, b.y, b.z, b.w);
    *(uint2*)(reps + (size_t)(wave*NB + r) * ND + lane*8) = pk;
    #pragma unroll
    for (int off = 32; off; off >>= 1) ss += __shfl_down(ss, off);
    if (lane == 0) norms[wave*NB + r] = ss;
  }
  __syncthreads();
  if (wave == 3) {
    float ss = 0.f;
    #pragma unroll
    for (int i = 0; i < 2; ++i) {
      float4 a = ((float4*)s1)[lane*2+i];
      float4 b = ((float4*)s2)[lane*2+i];
      float d0 = a.x - b.x + 1e-6f, d1 = a.y - b.y + 1e-6f;
      float d2 = a.z - b.z + 1e-6f, d3 = a.w - b.w + 1e-6f;
      ss += d0*d0 + d1*d1 + d2*d2 + d3*d3;
    }
    #pragma unroll
    for (int off = 32; off; off >>= 1) ss += __shfl_down(ss, off);
    if (lane == 0) { dist12[r] = sqrtf(ss); minsq[r] = 0x7F800000u; }
  }
}

// Read one 32-byte f8f6f4 operand fragment (8 dwords) from a 128B-row LDS
// tile: lane holds row [row], k-bytes [ks*64 + hi*32 .. +31]; granules are
// XOR-swizzled (slot ^ (row&7)) matching the staging-side source swizzle.
__device__ __forceinline__ i32x8 rd_op(const u8* __restrict__ S, int row,
                                       int ks, int hi) {
  const int sw = row & 7;
  const int s0 = ks*4 + hi*2;
  const i32x4 lo = *(const i32x4*)&S[row*BK + ((s0 ^ sw) << 4)];
  const i32x4 h  = *(const i32x4*)&S[row*BK + (((s0+1) ^ sw) << 4)];
  i32x8 r;
  r[0]=lo[0]; r[1]=lo[1]; r[2]=lo[2]; r[3]=lo[3];
  r[4]=h[0];  r[5]=h[1];  r[6]=h[2];  r[7]=h[3];
  return r;
}

#define MFMA8(a,b,c) __builtin_amdgcn_mfma_scale_f32_32x32x64_f8f6f4(          \
    (a), (b), (c), 0, 0, 0, SCL, 0, SCL)

// Fused distance-GEMM (MX-fp8, scale=1.0) + per-row min + diagonal picks.
// 128x128 tile, BK=128 fp8 (NKT=4 -> half the vmcnt(0) drains of bf16 BK=64).
// 8 waves (4M x 2N), wave-tile 32x64 = 1x2 frags of 32x32 -> acc is only
// 2 x f32x16 = 32 VGPR (R8's 4x f32x16 + launch_bounds(,4) spilled to
// scratch: WRITE_SIZE 405 MB, VGPR capped at 64 -> 167 us. No min-wave
// bound here; target ~110 VGPR, 2 blocks/CU).
// Grid dim3(32,96) M-fastest (R5 lesson: XCD swizzle quadrupled FETCH).
// LDS linear; XOR swizzle on per-lane GLOBAL source granule (m173 pattern).
__global__ __launch_bounds__(512) void gemm_min(
    const u8* __restrict__ reps, const float* __restrict__ norms,
    u32* __restrict__ minsq, float* __restrict__ lpos1,
    float* __restrict__ lpos2)
{
  __shared__ u8 As[ASZ];
  __shared__ u8 Bs[BSZ];
  const int tid  = threadIdx.x;
  const int lane = tid & 63;
  const int wave = tid >> 6;          // 0..7
  const int wr = wave >> 1;           // 0..3 (M quarter: 32 rows each)
  const int wc = wave & 1;            // 0..1 (N half: 64 cols each)
  const int lc = lane & 31;           // col within 32x32 frag
  const int hi = lane >> 5;           // k-half / row-offset selector

  const int rowBase = blockIdx.x * BM;   // ts rows
  const int colBase = blockIdx.y * BN;   // reps rows

  // Staging: rows are 128 B (8 granules); one GLD16 covers 8 rows (1 KiB).
  // A = 16 chunks (2/wave), B = 16 chunks (2/wave).
  const int rloc = lane >> 3;          // row within 8-row chunk
  const int sp   = lane & 7;           // physical granule slot
  const int g    = sp ^ rloc;          // swizzled source granule
  const u8* srcA[2]; u8* dstA[2];
  const u8* srcB[2]; u8* dstB[2];
  #pragma unroll
  for (int i = 0; i < 2; ++i) {
    const int r = wave*16 + i*8 + rloc;           // tile-local row 0..127
    srcA[i] = reps + (size_t)(rowBase + r) * ND + g*16;
    dstA[i] = &As[(wave*16 + i*8) * BK];
    srcB[i] = reps + (size_t)(colBase + r) * ND + g*16;
    dstB[i] = &Bs[(wave*16 + i*8) * BK];
  }

  f32x16 acc0 = {}, acc1 = {};

  for (int kt = 0; kt < NKT; ++kt) {
    const int koff = kt * BK;
    #pragma unroll
    for (int i = 0; i < 2; ++i) { GLD16(srcA[i] + koff, dstA[i]);
                                  GLD16(srcB[i] + koff, dstB[i]); }
    __syncthreads();   // vmcnt(0) drain + barrier (4x per block)

    #pragma unroll
    for (int ks = 0; ks < 2; ++ks) {
      const i32x8 a0 = rd_op(As, wr*32      + lc, ks, hi);
      const i32x8 b0 = rd_op(Bs, wc*64      + lc, ks, hi);
      const i32x8 b1 = rd_op(Bs, wc*64 + 32 + lc, ks, hi);
      acc0 = MFMA8(a0, b0, acc0);
      acc1 = MFMA8(a0, b1, acc1);
    }
    __syncthreads();
  }

  // Epilogue. 32x32 C layout: col = lane&31, row = (reg&3)+8*(reg>>2)+4*hi.
  // For fixed reg, one 32-lane half holds all 32 cols of one row: 5-step
  // shuffle-xor min within the half (xor<32 stays in-half); both halves
  // reduce their own rows independently.
  const float nc0 = norms[colBase + wc*64      + lc];
  const float nc1 = norms[colBase + wc*64 + 32 + lc];
  const int   c0g = colBase + wc*64      + lc;
  const int   c1g = colBase + wc*64 + 32 + lc;
  const float INF = __builtin_inff();

  #pragma unroll
  for (int reg = 0; reg < 16; ++reg) {
    const int r_g = rowBase + wr*32 + (reg&3) + 8*(reg>>2) + 4*hi;
    const float ntr = norms[r_g];
    const float sq0 = ntr + nc0 - 2.0f * acc0[reg];
    const float sq1 = ntr + nc1 - 2.0f * acc1[reg];
    if (c0g == r_g + NB)   lpos1[r_g] = sq0;   // unique writer
    if (c0g == r_g + 2*NB) lpos2[r_g] = sq0;
    if (c1g == r_g + NB)   lpos1[r_g] = sq1;
    if (c1g == r_g + 2*NB) lpos2[r_g] = sq1;
    const bool e0 = (c0g == r_g) || (c0g == r_g+NB) || (c0g == r_g+2*NB);
    const bool e1 = (c1g == r_g) || (c1g == r_g+NB) || (c1g == r_g+2*NB);
    float vm = fminf(e0 ? INF : fmaxf(sq0, 0.0f),
                     e1 ? INF : fmaxf(sq1, 0.0f));
    #pragma unroll
    for (int off = 1; off < 32; off <<= 1)
      vm = fminf(vm, __shfl_xor(vm, off));
    if (lc == 0)
      atomicMin(minsq + r_g, __float_as_uint(vm));  // nonneg floats as uints
  }
}

__global__ __launch_bounds__(1024) void finalize(
    const float* __restrict__ lpos1, const float* __restrict__ lpos2,
    const float* __restrict__ dist12, const u32* __restrict__ minsq,
    float* __restrict__ out)
{
  __shared__ float red[16];
  const int tid = threadIdx.x;
  float s = 0.f;
  for (int r = tid; r < NB; r += 1024) {
    float l1 = sqrtf(fmaxf(lpos1[r], 0.f));
    float l2 = sqrtf(fmaxf(lpos2[r], 0.f));
    float neg = sqrtf(__uint_as_float(minsq[r]));   // already clamped >= 0
    float pos = l1 + l2 + dist12[r];
    s += fmaxf(pos - neg + 0.1f, 0.f) + fmaxf(l1, l2);
  }
  #pragma unroll
  for (int off = 32; off; off >>= 1) s += __shfl_down(s, off);
  if ((tid & 63) == 0) red[tid >> 6] = s;
  __syncthreads();
  if (tid == 0) {
    float t = 0.f;
    #pragma unroll
    for (int i = 0; i < 16; ++i) t += red[i];
    out[0] = t * (1.0f / NB);
  }
}

extern "C" void kernel_launch(void* const* d_in, const int* in_sizes, int n_in,
                              void* d_out, int out_size, void* d_ws, size_t ws_size,
                              hipStream_t stream) {
  const float* ts = (const float*)d_in[0];
  const float* i1 = (const float*)d_in[1];
  const float* i2 = (const float*)d_in[2];
  float* out = (float*)d_out;

  char* p = (char*)d_ws;
  u8* reps     = (u8*)p;             p += (size_t)NREPS * ND * sizeof(u8);   // 6.3 MB
  float* norms = (float*)p;          p += (size_t)NREPS * sizeof(float);
  float* dist12 = (float*)p;         p += (size_t)NB * sizeof(float);
  u32* minsq   = (u32*)p;            p += (size_t)NB * sizeof(u32);
  float* lpos1 = (float*)p;          p += (size_t)NB * sizeof(float);
  float* lpos2 = (float*)p;          p += (size_t)NB * sizeof(float);

  prep_all<<<NB, 256, 0, stream>>>(ts, i1, i2, reps, norms, dist12, minsq);
  dim3 grid(NB / BM, NREPS / BN);   // 32 x 96, M-fastest (L2 locality)
  gemm_min<<<grid, 512, 0, stream>>>(reps, norms, minsq, lpos1, lpos2);
  finalize<<<1, 1024, 0, stream>>>(lpos1, lpos2, dist12, minsq, out);
}